// Round 2
// baseline (536.107 us; speedup 1.0000x reference)
//
#include <hip/hip_runtime.h>
#include <math.h>

#define DEV __device__ __forceinline__

typedef unsigned int u32;
typedef unsigned short u16;
typedef __attribute__((ext_vector_type(4)))  float f32x4;
typedef __attribute__((ext_vector_type(16))) float f32x16;
typedef __attribute__((ext_vector_type(2)))  float f32x2;
typedef __attribute__((ext_vector_type(8)))  __bf16 bf16x8;
typedef __attribute__((ext_vector_type(4)))  u32 u32x4;

constexpr int B_ = 4, S_ = 2048, H_ = 16;
// D=1024, HD=64, HD2=32, rows = B*S = 8192, qkv width = 3072

DEV u16 f2bf(float f) {
    u32 u = __float_as_uint(f);
    return (u16)((u + 0x7fffu + ((u >> 16) & 1u)) >> 16);
}
DEV float bf2f(u16 x) { return __uint_as_float((u32)x << 16); }

DEV u32 cvtpk_bf16(float lo, float hi) {
    u32 r;
    asm("v_cvt_pk_bf16_f32 %0, %1, %2" : "=v"(r) : "v"(lo), "v"(hi));
    return r;
}

DEV void g2lds16(const void* g, void* l) {
    __builtin_amdgcn_global_load_lds(
        (__attribute__((address_space(1))) void*)(uintptr_t)g,
        (__attribute__((address_space(3))) void*)(u32)(uintptr_t)l,
        16, 0, 0);
}

// ---------------- prep: cos/sin table + fused qkv bias ----------------
__global__ void prep_kernel(const float* __restrict__ theta,
                            const float* __restrict__ qb,
                            const float* __restrict__ vb,
                            f32x2* __restrict__ tab,
                            float* __restrict__ qkvbias) {
    const int idx = blockIdx.x * 256 + threadIdx.x;   // 65536 threads = 2048*32
    if (idx < 3072)
        qkvbias[idx] = idx < 1024 ? qb[idx] : (idx < 2048 ? 0.0f : vb[idx - 2048]);
    const int s = idx >> 5, f = idx & 31;
    // mimic reference f32 op chain; pow/cos in f64 for accuracy
    const double MEL = 2595.0 * log10(1.0 + 8000.0 / 700.0);
    float step = (float)MEL / 31.0f;
    float linf = (float)f * step;
    float y = linf / 2595.0f;
    double p = pow(10.0, (double)y);
    float pf = (float)p;
    float t1 = theta[0] / 220.0f * 700.0f;
    float freq = t1 * (pf - 1.0f) / 1000.0f;
    float ang = (float)s * freq;        // f32 product, like reference
    double da = (double)ang;
    f32x2 cs;
    cs.x = (float)cos(da);
    cs.y = (float)sin(da);
    tab[idx] = cs;
}

// ---------------- fp32 -> bf16 conversion ----------------
__global__ void cvt_kernel(const float* __restrict__ src, u16* __restrict__ dst, int n4) {
    int i = blockIdx.x * 256 + threadIdx.x;
    if (i >= n4) return;
    float4 v = reinterpret_cast<const float4*>(src)[i];
    ushort4 o;
    o.x = f2bf(v.x); o.y = f2bf(v.y); o.z = f2bf(v.z); o.w = f2bf(v.w);
    reinterpret_cast<ushort4*>(dst)[i] = o;
}

// ---------------- GEMM  C[M,N] = A[M,K] * Bt[N,K]^T (+bias) ----------------
// m97 structure: 128x128 tile, BK=64, 4 waves (2x2), 16x16x32 bf16 MFMA,
// global_load_lds width 16, single-buffered LDS. lda = A row stride (elems).
template <int OUT_BF16, int HAS_BIAS>
__global__ __launch_bounds__(256)
void gemm_bt(const u16* __restrict__ A, const u16* __restrict__ Bt,
             const float* __restrict__ bias, void* __restrict__ Cout,
             int M, int N, int K, int lda) {
    __shared__ u16 lA[128 * 64];
    __shared__ u16 lB[128 * 64];
    const int tid = threadIdx.x;
    const int lane = tid & 63, wave = tid >> 6;
    const int wr = wave >> 1, wc = wave & 1;
    const int m0 = blockIdx.x * 128, n0 = blockIdx.y * 128;
    const int fr = lane & 15, fk = (lane >> 4) * 8;
    const int stRow = tid >> 3;            // 0..31
    const int stCol = (tid & 7) * 8;       // 0..56

    f32x4 acc[4][4];
#pragma unroll
    for (int m = 0; m < 4; ++m)
#pragma unroll
        for (int n = 0; n < 4; ++n) acc[m][n] = (f32x4)0.0f;

    for (int k0 = 0; k0 < K; k0 += 64) {
#pragma unroll
        for (int i = 0; i < 4; ++i) {
            int row = i * 32 + stRow;
            int e = row * 64 + stCol;
            g2lds16(A + (size_t)(m0 + row) * lda + (k0 + stCol), &lA[e]);
            g2lds16(Bt + (size_t)(n0 + row) * K + (k0 + stCol), &lB[e]);
        }
        __syncthreads();
#pragma unroll
        for (int kk = 0; kk < 2; ++kk) {
            bf16x8 af[4], bg[4];
#pragma unroll
            for (int m = 0; m < 4; ++m)
                af[m] = *reinterpret_cast<const bf16x8*>(&lA[(wr * 64 + m * 16 + fr) * 64 + kk * 32 + fk]);
#pragma unroll
            for (int n = 0; n < 4; ++n)
                bg[n] = *reinterpret_cast<const bf16x8*>(&lB[(wc * 64 + n * 16 + fr) * 64 + kk * 32 + fk]);
#pragma unroll
            for (int m = 0; m < 4; ++m)
#pragma unroll
                for (int n = 0; n < 4; ++n)
                    acc[m][n] = __builtin_amdgcn_mfma_f32_16x16x32_bf16(af[m], bg[n], acc[m][n], 0, 0, 0);
        }
        __syncthreads();
    }
    // epilogue: C/D layout col = lane&15, row = (lane>>4)*4 + j
#pragma unroll
    for (int n = 0; n < 4; ++n) {
        int col = n0 + wc * 64 + n * 16 + fr;
        float bv = HAS_BIAS ? bias[col] : 0.0f;
#pragma unroll
        for (int m = 0; m < 4; ++m) {
            int r0 = m0 + wr * 64 + m * 16 + (lane >> 4) * 4;
#pragma unroll
            for (int j = 0; j < 4; ++j) {
                float v = acc[m][n][j] + bv;
                if (OUT_BF16)
                    ((u16*)Cout)[(size_t)(r0 + j) * N + col] = f2bf(v);
                else
                    ((float*)Cout)[(size_t)(r0 + j) * N + col] = v;
            }
        }
    }
}

// ---------------- rope (in-place on q,k) + V transpose ----------------
__global__ __launch_bounds__(256)
void rope_vt_kernel(u16* __restrict__ qkv, const f32x2* __restrict__ tab,
                    u16* __restrict__ vT) {
    __shared__ u16 lv[64][66];
    const int t = threadIdx.x;
    const int sblk = blockIdx.x;       // 0..31
    const int bh = blockIdx.y;         // 0..63
    const int b = bh >> 4, h = bh & 15;
    const int s0 = sblk * 64;
    const int f = t & 31, sl0 = t >> 5;
#pragma unroll
    for (int i = 0; i < 8; ++i) {
        int sl = i * 8 + sl0;
        int s = s0 + sl;
        f32x2 cs = tab[(s << 5) + f];
        size_t ro = (size_t)(b * S_ + s) * 3072 + h * 64 + 2 * f;
        u32* pq = (u32*)(qkv + ro);
        u32 vq = *pq;
        float a = bf2f((u16)(vq & 0xffff)), bb = bf2f((u16)(vq >> 16));
        *pq = (u32)f2bf(a * cs.x - bb * cs.y) | ((u32)f2bf(a * cs.y + bb * cs.x) << 16);
        u32* pk = (u32*)(qkv + ro + 1024);
        u32 vk = *pk;
        float a2 = bf2f((u16)(vk & 0xffff)), b2 = bf2f((u16)(vk >> 16));
        *pk = (u32)f2bf(a2 * cs.x - b2 * cs.y) | ((u32)f2bf(a2 * cs.y + b2 * cs.x) << 16);
    }
    // stage V tile [64 s][64 hd] then write transposed [hd][s]
#pragma unroll
    for (int i = 0; i < 4; ++i) {
        int u = i * 256 + t;
        int sl = u >> 4, hd = (u & 15) * 4;
        ushort4 vv = *(const ushort4*)(qkv + (size_t)(b * S_ + s0 + sl) * 3072 + 2048 + h * 64 + hd);
        lv[sl][hd] = vv.x; lv[sl][hd + 1] = vv.y; lv[sl][hd + 2] = vv.z; lv[sl][hd + 3] = vv.w;
    }
    __syncthreads();
#pragma unroll
    for (int i = 0; i < 4; ++i) {
        int u = i * 256 + t;
        int hd = u >> 4, sl = (u & 15) * 4;
        ushort4 ov;
        ov.x = lv[sl][hd]; ov.y = lv[sl + 1][hd]; ov.z = lv[sl + 2][hd]; ov.w = lv[sl + 3][hd];
        *(ushort4*)(vT + ((size_t)bh * 64 + hd) * S_ + s0 + sl) = ov;
    }
}

// ---------------- flash attention ----------------
// 4 waves x 32 q-rows, KVBLK=32, swapped QK^T (mfma(K,Q)), O^T = mfma(V^T, P^T).
// Output written into the dead V-section of qkvlin (cols 2048..3071).
__global__ __launch_bounds__(256)
void attn_kernel(u16* __restrict__ qkv, const u16* __restrict__ vT) {
    const int lane = threadIdx.x & 63;
    const int wave = threadIdx.x >> 6;
    const int qblk = blockIdx.x;       // 0..15
    const int bh = blockIdx.y;         // 0..63
    const int b = bh >> 4, h = bh & 15;
    const int q0 = qblk * 128 + wave * 32;
    const int lr = lane & 31;
    const int hi = lane >> 5;
    const int fo = hi * 8;

    bf16x8 qf[4];
    const u16* qrow = qkv + (size_t)(b * S_ + q0 + lr) * 3072 + h * 64 + fo;
#pragma unroll
    for (int ks = 0; ks < 4; ++ks)
        qf[ks] = *reinterpret_cast<const bf16x8*>(qrow + ks * 16);

    const u16* krow = qkv + (size_t)(b * S_ + lr) * 3072 + 1024 + h * 64 + fo;
    const u16* vrow = vT + ((size_t)bh * 64 + lr) * S_ + fo;

    f32x16 o0 = (f32x16)0.0f, o1 = (f32x16)0.0f;
    float m = -3.0e38f, l = 0.0f;
    const float c1 = 0.125f * 1.44269504088896340736f;  // scale * log2(e)

    for (int kv0 = 0; kv0 < S_; kv0 += 32) {
        const u16* kb = krow + (size_t)kv0 * 3072;
        bf16x8 kf0 = *reinterpret_cast<const bf16x8*>(kb);
        bf16x8 kf1 = *reinterpret_cast<const bf16x8*>(kb + 16);
        bf16x8 kf2 = *reinterpret_cast<const bf16x8*>(kb + 32);
        bf16x8 kf3 = *reinterpret_cast<const bf16x8*>(kb + 48);
        f32x16 s = (f32x16)0.0f;
        s = __builtin_amdgcn_mfma_f32_32x32x16_bf16(kf0, qf[0], s, 0, 0, 0);
        s = __builtin_amdgcn_mfma_f32_32x32x16_bf16(kf1, qf[1], s, 0, 0, 0);
        s = __builtin_amdgcn_mfma_f32_32x32x16_bf16(kf2, qf[2], s, 0, 0, 0);
        s = __builtin_amdgcn_mfma_f32_32x32x16_bf16(kf3, qf[3], s, 0, 0, 0);

        bf16x8 vf00 = *reinterpret_cast<const bf16x8*>(vrow + kv0);
        bf16x8 vf01 = *reinterpret_cast<const bf16x8*>(vrow + kv0 + 16);
        bf16x8 vf10 = *reinterpret_cast<const bf16x8*>(vrow + (size_t)32 * S_ + kv0);
        bf16x8 vf11 = *reinterpret_cast<const bf16x8*>(vrow + (size_t)32 * S_ + kv0 + 16);

        // online softmax: lane lr owns q-row lr; k rows crow(r,hi)=(r&3)+8*(r>>2)+4*hi
        float pv[16];
        float mt = -3.0e38f;
#pragma unroll
        for (int r = 0; r < 16; ++r) { pv[r] = s[r] * c1; mt = fmaxf(mt, pv[r]); }
        mt = fmaxf(mt, __shfl_xor(mt, 32));
        float mn = fmaxf(m, mt);
        float alpha = exp2f(m - mn);
        m = mn;
        float ps = 0.0f;
#pragma unroll
        for (int r = 0; r < 16; ++r) { pv[r] = exp2f(pv[r] - mn); ps += pv[r]; }
        l = l * alpha + ps;
        o0 = o0 * alpha;
        o1 = o1 * alpha;

        // pack P -> bf16 B-frags: lane needs P[q=lr][kv=hi*8+r'+16*hf]
        u32 d00, d01, d02, d03, d10, d11, d12, d13;
        {
            u32 a0 = cvtpk_bf16(pv[0], pv[1]);
            u32 a1 = cvtpk_bf16(pv[2], pv[3]);
            u32 b0 = cvtpk_bf16(pv[4], pv[5]);
            u32 b1 = cvtpk_bf16(pv[6], pv[7]);
            u32 xa0 = (u32)__shfl_xor((int)a0, 32), xa1 = (u32)__shfl_xor((int)a1, 32);
            u32 xb0 = (u32)__shfl_xor((int)b0, 32), xb1 = (u32)__shfl_xor((int)b1, 32);
            d00 = hi ? xb0 : a0;  d01 = hi ? xb1 : a1;
            d02 = hi ? b0 : xa0;  d03 = hi ? b1 : xa1;
        }
        {
            u32 a0 = cvtpk_bf16(pv[8], pv[9]);
            u32 a1 = cvtpk_bf16(pv[10], pv[11]);
            u32 b0 = cvtpk_bf16(pv[12], pv[13]);
            u32 b1 = cvtpk_bf16(pv[14], pv[15]);
            u32 xa0 = (u32)__shfl_xor((int)a0, 32), xa1 = (u32)__shfl_xor((int)a1, 32);
            u32 xb0 = (u32)__shfl_xor((int)b0, 32), xb1 = (u32)__shfl_xor((int)b1, 32);
            d10 = hi ? xb0 : a0;  d11 = hi ? xb1 : a1;
            d12 = hi ? b0 : xa0;  d13 = hi ? b1 : xa1;
        }
        u32x4 t0 = {d00, d01, d02, d03};
        u32x4 t1 = {d10, d11, d12, d13};
        bf16x8 p0 = __builtin_bit_cast(bf16x8, t0);
        bf16x8 p1 = __builtin_bit_cast(bf16x8, t1);

        o0 = __builtin_amdgcn_mfma_f32_32x32x16_bf16(vf00, p0, o0, 0, 0, 0);
        o0 = __builtin_amdgcn_mfma_f32_32x32x16_bf16(vf01, p1, o0, 0, 0, 0);
        o1 = __builtin_amdgcn_mfma_f32_32x32x16_bf16(vf10, p0, o1, 0, 0, 0);
        o1 = __builtin_amdgcn_mfma_f32_32x32x16_bf16(vf11, p1, o1, 0, 0, 0);
    }

    l += __shfl_xor(l, 32);
    float inv = 1.0f / l;
    u16* orow = qkv + (size_t)(b * S_ + q0 + lr) * 3072 + 2048 + h * 64;
#pragma unroll
    for (int g = 0; g < 4; ++g) {
        ushort4 w0, w1;
        w0.x = f2bf(o0[4 * g + 0] * inv); w0.y = f2bf(o0[4 * g + 1] * inv);
        w0.z = f2bf(o0[4 * g + 2] * inv); w0.w = f2bf(o0[4 * g + 3] * inv);
        *(ushort4*)(orow + 8 * g + 4 * hi) = w0;
        w1.x = f2bf(o1[4 * g + 0] * inv); w1.y = f2bf(o1[4 * g + 1] * inv);
        w1.z = f2bf(o1[4 * g + 2] * inv); w1.w = f2bf(o1[4 * g + 3] * inv);
        *(ushort4*)(orow + 32 + 8 * g + 4 * hi) = w1;
    }
}

// ---------------- launch ----------------
extern "C" void kernel_launch(void* const* d_in, const int* in_sizes, int n_in,
                              void* d_out, int out_size, void* d_ws, size_t ws_size,
                              hipStream_t stream) {
    const float* x  = (const float*)d_in[0];
    const float* qw = (const float*)d_in[1];
    const float* qb = (const float*)d_in[2];
    const float* kw = (const float*)d_in[3];
    const float* vw = (const float*)d_in[4];
    const float* vb = (const float*)d_in[5];
    const float* ow = (const float*)d_in[6];
    const float* ob = (const float*)d_in[7];
    const float* th = (const float*)d_in[8];

    char* ws = (char*)d_ws;
    f32x2* tab  = (f32x2*)ws;            ws += (size_t)2048 * 32 * 8;
    float* qkvb = (float*)ws;            ws += 3072 * 4;
    u16* xb     = (u16*)ws;              ws += (size_t)8192 * 1024 * 2;
    u16* wqkv   = (u16*)ws;              ws += (size_t)3072 * 1024 * 2;
    u16* wo     = (u16*)ws;              ws += (size_t)1024 * 1024 * 2;
    u16* qkvlin = (u16*)ws;              ws += (size_t)8192 * 3072 * 2;
    u16* vT     = (u16*)ws;              ws += (size_t)64 * 64 * 2048 * 2;

    prep_kernel<<<256, 256, 0, stream>>>(th, qb, vb, tab, qkvb);
    cvt_kernel<<<8192, 256, 0, stream>>>(x, xb, 2097152);
    cvt_kernel<<<1024, 256, 0, stream>>>(qw, wqkv, 262144);
    cvt_kernel<<<1024, 256, 0, stream>>>(kw, wqkv + 1024 * 1024, 262144);
    cvt_kernel<<<1024, 256, 0, stream>>>(vw, wqkv + 2 * 1024 * 1024, 262144);
    cvt_kernel<<<1024, 256, 0, stream>>>(ow, wo, 262144);
    gemm_bt<1, 1><<<dim3(64, 24), 256, 0, stream>>>(xb, wqkv, qkvb, qkvlin, 8192, 3072, 1024, 1024);
    rope_vt_kernel<<<dim3(32, 64), 256, 0, stream>>>(qkvlin, tab, vT);
    attn_kernel<<<dim3(16, 64), 256, 0, stream>>>(qkvlin, vT);
    gemm_bt<0, 1><<<dim3(64, 8), 256, 0, stream>>>(qkvlin + 2048, wo, ob, d_out, 8192, 1024, 1024, 3072);
}

// Round 7
// 471.236 us; speedup vs baseline: 1.1377x; 1.1377x over previous
//
#include <hip/hip_runtime.h>
#include <math.h>

#define DEV __device__ __forceinline__

typedef unsigned int u32;
typedef unsigned short u16;
typedef __attribute__((ext_vector_type(4)))  float f32x4;
typedef __attribute__((ext_vector_type(16))) float f32x16;
typedef __attribute__((ext_vector_type(2)))  float f32x2;
typedef __attribute__((ext_vector_type(8)))  __bf16 bf16x8;
typedef __attribute__((ext_vector_type(4)))  u32 u32x4;

constexpr int B_ = 4, S_ = 2048, H_ = 16;
// D=1024, HD=64, HD2=32, rows = B*S = 8192, qkv width = 3072

DEV u16 f2bf(float f) {
    u32 u = __float_as_uint(f);
    return (u16)((u + 0x7fffu + ((u >> 16) & 1u)) >> 16);
}
DEV float bf2f(u16 x) { return __uint_as_float((u32)x << 16); }

DEV u32 cvtpk_bf16(float lo, float hi) {
    u32 r;
    asm("v_cvt_pk_bf16_f32 %0, %1, %2" : "=v"(r) : "v"(lo), "v"(hi));
    return r;
}

DEV void g2lds16(const void* g, void* l) {
    __builtin_amdgcn_global_load_lds(
        (__attribute__((address_space(1))) void*)(uintptr_t)g,
        (__attribute__((address_space(3))) void*)(u32)(uintptr_t)l,
        16, 0, 0);
}

// ---------------- prep: cos/sin table + fused qkv bias ----------------
__global__ void prep_kernel(const float* __restrict__ theta,
                            const float* __restrict__ qb,
                            const float* __restrict__ vb,
                            f32x2* __restrict__ tab,
                            float* __restrict__ qkvbias) {
    const int idx = blockIdx.x * 256 + threadIdx.x;   // 65536 threads = 2048*32
    if (idx < 3072)
        qkvbias[idx] = idx < 1024 ? qb[idx] : (idx < 2048 ? 0.0f : vb[idx - 2048]);
    const int s = idx >> 5, f = idx & 31;
    // mimic reference f32 op chain; pow/cos in f64 for accuracy
    const double MEL = 2595.0 * log10(1.0 + 8000.0 / 700.0);
    float step = (float)MEL / 31.0f;
    float linf = (float)f * step;
    float y = linf / 2595.0f;
    double p = pow(10.0, (double)y);
    float pf = (float)p;
    float t1 = theta[0] / 220.0f * 700.0f;
    float freq = t1 * (pf - 1.0f) / 1000.0f;
    float ang = (float)s * freq;        // f32 product, like reference
    double da = (double)ang;
    f32x2 cs;
    cs.x = (float)cos(da);
    cs.y = (float)sin(da);
    tab[idx] = cs;
}

// ---------------- fp32 -> bf16 conversion (x) ----------------
__global__ void cvt_kernel(const float* __restrict__ src, u16* __restrict__ dst, int n4) {
    int i = blockIdx.x * 256 + threadIdx.x;
    if (i >= n4) return;
    float4 v = reinterpret_cast<const float4*>(src)[i];
    ushort4 o;
    o.x = f2bf(v.x); o.y = f2bf(v.y); o.z = f2bf(v.z); o.w = f2bf(v.w);
    reinterpret_cast<ushort4*>(dst)[i] = o;
}

// ---------------- fused weight conversion: qw|kw|vw|ow -> contiguous dst ----
// 4 segments of 262144 float4-groups each; segment is block-uniform (1024
// blocks/segment, no straddle).
__global__ void cvt4_kernel(const float* __restrict__ s0, const float* __restrict__ s1,
                            const float* __restrict__ s2, const float* __restrict__ s3,
                            u16* __restrict__ dst) {
    int i = blockIdx.x * 256 + threadIdx.x;          // 0 .. 1048575
    int seg = i >> 18;
    const float* src = seg == 0 ? s0 : seg == 1 ? s1 : seg == 2 ? s2 : s3;
    float4 v = reinterpret_cast<const float4*>(src)[i & 0x3FFFF];
    ushort4 o;
    o.x = f2bf(v.x); o.y = f2bf(v.y); o.z = f2bf(v.z); o.w = f2bf(v.w);
    reinterpret_cast<ushort4*>(dst)[i] = o;
}

// ---------------- GEMM  C[M,N] = A[M,K] * Bt[N,K]^T (+bias) ----------------
// m97 structure: 128x128 tile, BK=64, 4 waves (2x2), 16x16x32 bf16 MFMA,
// global_load_lds width 16, single-buffered LDS. lda = A row stride (elems).
template <int OUT_BF16, int HAS_BIAS>
__global__ __launch_bounds__(256)
void gemm_bt(const u16* __restrict__ A, const u16* __restrict__ Bt,
             const float* __restrict__ bias, void* __restrict__ Cout,
             int M, int N, int K, int lda) {
    __shared__ u16 lA[128 * 64];
    __shared__ u16 lB[128 * 64];
    const int tid = threadIdx.x;
    const int lane = tid & 63, wave = tid >> 6;
    const int wr = wave >> 1, wc = wave & 1;
    const int m0 = blockIdx.x * 128, n0 = blockIdx.y * 128;
    const int fr = lane & 15, fk = (lane >> 4) * 8;
    const int stRow = tid >> 3;            // 0..31
    const int stCol = (tid & 7) * 8;       // 0..56

    f32x4 acc[4][4];
#pragma unroll
    for (int m = 0; m < 4; ++m)
#pragma unroll
        for (int n = 0; n < 4; ++n) acc[m][n] = (f32x4)0.0f;

    for (int k0 = 0; k0 < K; k0 += 64) {
#pragma unroll
        for (int i = 0; i < 4; ++i) {
            int row = i * 32 + stRow;
            int e = row * 64 + stCol;
            g2lds16(A + (size_t)(m0 + row) * lda + (k0 + stCol), &lA[e]);
            g2lds16(Bt + (size_t)(n0 + row) * K + (k0 + stCol), &lB[e]);
        }
        __syncthreads();
#pragma unroll
        for (int kk = 0; kk < 2; ++kk) {
            bf16x8 af[4], bg[4];
#pragma unroll
            for (int m = 0; m < 4; ++m)
                af[m] = *reinterpret_cast<const bf16x8*>(&lA[(wr * 64 + m * 16 + fr) * 64 + kk * 32 + fk]);
#pragma unroll
            for (int n = 0; n < 4; ++n)
                bg[n] = *reinterpret_cast<const bf16x8*>(&lB[(wc * 64 + n * 16 + fr) * 64 + kk * 32 + fk]);
#pragma unroll
            for (int m = 0; m < 4; ++m)
#pragma unroll
                for (int n = 0; n < 4; ++n)
                    acc[m][n] = __builtin_amdgcn_mfma_f32_16x16x32_bf16(af[m], bg[n], acc[m][n], 0, 0, 0);
        }
        __syncthreads();
    }
    // epilogue: C/D layout col = lane&15, row = (lane>>4)*4 + j
#pragma unroll
    for (int n = 0; n < 4; ++n) {
        int col = n0 + wc * 64 + n * 16 + fr;
        float bv = HAS_BIAS ? bias[col] : 0.0f;
#pragma unroll
        for (int m = 0; m < 4; ++m) {
            int r0 = m0 + wr * 64 + m * 16 + (lane >> 4) * 4;
#pragma unroll
            for (int j = 0; j < 4; ++j) {
                float v = acc[m][n][j] + bv;
                if (OUT_BF16)
                    ((u16*)Cout)[(size_t)(r0 + j) * N + col] = f2bf(v);
                else
                    ((float*)Cout)[(size_t)(r0 + j) * N + col] = v;
            }
        }
    }
}

// ---------------- rope (in-place on q,k) + V transpose ----------------
__global__ __launch_bounds__(256)
void rope_vt_kernel(u16* __restrict__ qkv, const f32x2* __restrict__ tab,
                    u16* __restrict__ vT) {
    __shared__ u16 lv[64][66];
    const int t = threadIdx.x;
    const int sblk = blockIdx.x;       // 0..31
    const int bh = blockIdx.y;         // 0..63
    const int b = bh >> 4, h = bh & 15;
    const int s0 = sblk * 64;
    const int f = t & 31, sl0 = t >> 5;
#pragma unroll
    for (int i = 0; i < 8; ++i) {
        int sl = i * 8 + sl0;
        int s = s0 + sl;
        f32x2 cs = tab[(s << 5) + f];
        size_t ro = (size_t)(b * S_ + s) * 3072 + h * 64 + 2 * f;
        u32* pq = (u32*)(qkv + ro);
        u32 vq = *pq;
        float a = bf2f((u16)(vq & 0xffff)), bb = bf2f((u16)(vq >> 16));
        *pq = (u32)f2bf(a * cs.x - bb * cs.y) | ((u32)f2bf(a * cs.y + bb * cs.x) << 16);
        u32* pk = (u32*)(qkv + ro + 1024);
        u32 vk = *pk;
        float a2 = bf2f((u16)(vk & 0xffff)), b2 = bf2f((u16)(vk >> 16));
        *pk = (u32)f2bf(a2 * cs.x - b2 * cs.y) | ((u32)f2bf(a2 * cs.y + b2 * cs.x) << 16);
    }
    // stage V tile [64 s][64 hd] then write transposed [hd][s]
#pragma unroll
    for (int i = 0; i < 4; ++i) {
        int u = i * 256 + t;
        int sl = u >> 4, hd = (u & 15) * 4;
        ushort4 vv = *(const ushort4*)(qkv + (size_t)(b * S_ + s0 + sl) * 3072 + 2048 + h * 64 + hd);
        lv[sl][hd] = vv.x; lv[sl][hd + 1] = vv.y; lv[sl][hd + 2] = vv.z; lv[sl][hd + 3] = vv.w;
    }
    __syncthreads();
#pragma unroll
    for (int i = 0; i < 4; ++i) {
        int u = i * 256 + t;
        int hd = u >> 4, sl = (u & 15) * 4;
        ushort4 ov;
        ov.x = lv[sl][hd]; ov.y = lv[sl + 1][hd]; ov.z = lv[sl + 2][hd]; ov.w = lv[sl + 3][hd];
        *(ushort4*)(vT + ((size_t)bh * 64 + hd) * S_ + s0 + sl) = ov;
    }
}

// ---------------- flash attention ----------------
// 4 waves x 32 q-rows, KVBLK=32, swapped QK^T (mfma(K,Q)), O^T = mfma(V^T, P^T).
// Register-double-buffered K/V prefetch (unroll-2, literal buffer indices),
// defer-max (T13, THR=6 in log2 units), fmaf-folded scale, tree max.
// Output written into the dead V-section of qkvlin (cols 2048..3071).
__global__ __launch_bounds__(256)
void attn_kernel(u16* __restrict__ qkv, const u16* __restrict__ vT) {
    const int lane = threadIdx.x & 63;
    const int wave = threadIdx.x >> 6;
    const int qblk = blockIdx.x;       // 0..15
    const int bh = blockIdx.y;         // 0..63
    const int b = bh >> 4, h = bh & 15;
    const int q0 = qblk * 128 + wave * 32;
    const int lr = lane & 31;
    const int hi = lane >> 5;
    const int fo = hi * 8;

    bf16x8 qf[4];
    const u16* qrow = qkv + (size_t)(b * S_ + q0 + lr) * 3072 + h * 64 + fo;
#pragma unroll
    for (int ks = 0; ks < 4; ++ks)
        qf[ks] = *reinterpret_cast<const bf16x8*>(qrow + ks * 16);

    const u16* krow = qkv + (size_t)(b * S_ + lr) * 3072 + 1024 + h * 64 + fo;
    const u16* vrow = vT + ((size_t)bh * 64 + lr) * S_ + fo;

    f32x16 o0 = (f32x16)0.0f, o1 = (f32x16)0.0f;
    float ms = -3.0e38f, l = 0.0f;
    const float c1 = 0.125f * 1.44269504088896340736f;  // scale * log2(e)

    bf16x8 kb[2][4], vb[2][4];

#define LOADKV(BUF, KVOFF) do {                                                   \
        const u16* kp_ = krow + (size_t)((KVOFF) * 3072);                         \
        kb[BUF][0] = *reinterpret_cast<const bf16x8*>(kp_);                       \
        kb[BUF][1] = *reinterpret_cast<const bf16x8*>(kp_ + 16);                  \
        kb[BUF][2] = *reinterpret_cast<const bf16x8*>(kp_ + 32);                  \
        kb[BUF][3] = *reinterpret_cast<const bf16x8*>(kp_ + 48);                  \
        const u16* vp_ = vrow + (KVOFF);                                          \
        vb[BUF][0] = *reinterpret_cast<const bf16x8*>(vp_);                       \
        vb[BUF][1] = *reinterpret_cast<const bf16x8*>(vp_ + 16);                  \
        vb[BUF][2] = *reinterpret_cast<const bf16x8*>(vp_ + (size_t)(32 * S_));   \
        vb[BUF][3] = *reinterpret_cast<const bf16x8*>(vp_ + (size_t)(32 * S_) + 16); \
    } while (0)

#define COMPUTE(BUF) do {                                                         \
        f32x16 s = (f32x16)0.0f;                                                  \
        s = __builtin_amdgcn_mfma_f32_32x32x16_bf16(kb[BUF][0], qf[0], s, 0, 0, 0); \
        s = __builtin_amdgcn_mfma_f32_32x32x16_bf16(kb[BUF][1], qf[1], s, 0, 0, 0); \
        s = __builtin_amdgcn_mfma_f32_32x32x16_bf16(kb[BUF][2], qf[2], s, 0, 0, 0); \
        s = __builtin_amdgcn_mfma_f32_32x32x16_bf16(kb[BUF][3], qf[3], s, 0, 0, 0); \
        /* tree max over 16 raw scores */                                         \
        float t0_ = fmaxf(fmaxf(s[0], s[1]), fmaxf(s[2], s[3]));                  \
        float t1_ = fmaxf(fmaxf(s[4], s[5]), fmaxf(s[6], s[7]));                  \
        float t2_ = fmaxf(fmaxf(s[8], s[9]), fmaxf(s[10], s[11]));                \
        float t3_ = fmaxf(fmaxf(s[12], s[13]), fmaxf(s[14], s[15]));              \
        float mt = fmaxf(fmaxf(t0_, t1_), fmaxf(t2_, t3_));                       \
        mt = fmaxf(mt, __shfl_xor(mt, 32));                                       \
        float mts = mt * c1;                                                      \
        if (!__all(mts - ms <= 6.0f)) {                                           \
            float msn = fmaxf(ms, mts);                                           \
            float alpha = exp2f(ms - msn);                                        \
            ms = msn;                                                             \
            l *= alpha;                                                           \
            o0 = o0 * alpha;                                                      \
            o1 = o1 * alpha;                                                      \
        }                                                                         \
        float pv[16];                                                             \
        float ps = 0.0f;                                                          \
        _Pragma("unroll")                                                         \
        for (int r = 0; r < 16; ++r) {                                            \
            pv[r] = exp2f(fmaf(s[r], c1, -ms));                                   \
            ps += pv[r];                                                          \
        }                                                                         \
        l += ps;                                                                  \
        u32 d00, d01, d02, d03, d10, d11, d12, d13;                               \
        {                                                                         \
            u32 a0 = cvtpk_bf16(pv[0], pv[1]);                                    \
            u32 a1 = cvtpk_bf16(pv[2], pv[3]);                                    \
            u32 b0 = cvtpk_bf16(pv[4], pv[5]);                                    \
            u32 b1 = cvtpk_bf16(pv[6], pv[7]);                                    \
            u32 xa0 = (u32)__shfl_xor((int)a0, 32), xa1 = (u32)__shfl_xor((int)a1, 32); \
            u32 xb0 = (u32)__shfl_xor((int)b0, 32), xb1 = (u32)__shfl_xor((int)b1, 32); \
            d00 = hi ? xb0 : a0;  d01 = hi ? xb1 : a1;                            \
            d02 = hi ? b0 : xa0;  d03 = hi ? b1 : xa1;                            \
        }                                                                         \
        {                                                                         \
            u32 a0 = cvtpk_bf16(pv[8], pv[9]);                                    \
            u32 a1 = cvtpk_bf16(pv[10], pv[11]);                                  \
            u32 b0 = cvtpk_bf16(pv[12], pv[13]);                                  \
            u32 b1 = cvtpk_bf16(pv[14], pv[15]);                                  \
            u32 xa0 = (u32)__shfl_xor((int)a0, 32), xa1 = (u32)__shfl_xor((int)a1, 32); \
            u32 xb0 = (u32)__shfl_xor((int)b0, 32), xb1 = (u32)__shfl_xor((int)b1, 32); \
            d10 = hi ? xb0 : a0;  d11 = hi ? xb1 : a1;                            \
            d12 = hi ? b0 : xa0;  d13 = hi ? b1 : xa1;                            \
        }                                                                         \
        u32x4 tt0 = {d00, d01, d02, d03};                                         \
        u32x4 tt1 = {d10, d11, d12, d13};                                         \
        bf16x8 p0 = __builtin_bit_cast(bf16x8, tt0);                              \
        bf16x8 p1 = __builtin_bit_cast(bf16x8, tt1);                              \
        o0 = __builtin_amdgcn_mfma_f32_32x32x16_bf16(vb[BUF][0], p0, o0, 0, 0, 0); \
        o0 = __builtin_amdgcn_mfma_f32_32x32x16_bf16(vb[BUF][1], p1, o0, 0, 0, 0); \
        o1 = __builtin_amdgcn_mfma_f32_32x32x16_bf16(vb[BUF][2], p0, o1, 0, 0, 0); \
        o1 = __builtin_amdgcn_mfma_f32_32x32x16_bf16(vb[BUF][3], p1, o1, 0, 0, 0); \
    } while (0)

    LOADKV(0, 0);
    for (int t = 0; t < 64; t += 2) {
        LOADKV(1, (t + 1) * 32);                       // t+1 <= 63 always
        COMPUTE(0);
        int nk = (t + 2 < 64) ? (t + 2) * 32 : 63 * 32; // clamp: redundant reload on last
        LOADKV(0, nk);
        COMPUTE(1);
    }
#undef LOADKV
#undef COMPUTE

    l += __shfl_xor(l, 32);
    float inv = 1.0f / l;
    u16* orow = qkv + (size_t)(b * S_ + q0 + lr) * 3072 + 2048 + h * 64;
#pragma unroll
    for (int g = 0; g < 4; ++g) {
        ushort4 w0, w1;
        w0.x = f2bf(o0[4 * g + 0] * inv); w0.y = f2bf(o0[4 * g + 1] * inv);
        w0.z = f2bf(o0[4 * g + 2] * inv); w0.w = f2bf(o0[4 * g + 3] * inv);
        *(ushort4*)(orow + 8 * g + 4 * hi) = w0;
        w1.x = f2bf(o1[4 * g + 0] * inv); w1.y = f2bf(o1[4 * g + 1] * inv);
        w1.z = f2bf(o1[4 * g + 2] * inv); w1.w = f2bf(o1[4 * g + 3] * inv);
        *(ushort4*)(orow + 32 + 8 * g + 4 * hi) = w1;
    }
}

// ---------------- launch ----------------
extern "C" void kernel_launch(void* const* d_in, const int* in_sizes, int n_in,
                              void* d_out, int out_size, void* d_ws, size_t ws_size,
                              hipStream_t stream) {
    const float* x  = (const float*)d_in[0];
    const float* qw = (const float*)d_in[1];
    const float* qb = (const float*)d_in[2];
    const float* kw = (const float*)d_in[3];
    const float* vw = (const float*)d_in[4];
    const float* vb = (const float*)d_in[5];
    const float* ow = (const float*)d_in[6];
    const float* ob = (const float*)d_in[7];
    const float* th = (const float*)d_in[8];

    char* ws = (char*)d_ws;
    f32x2* tab  = (f32x2*)ws;            ws += (size_t)2048 * 32 * 8;
    float* qkvb = (float*)ws;            ws += 3072 * 4;
    u16* xb     = (u16*)ws;              ws += (size_t)8192 * 1024 * 2;
    u16* wqkv   = (u16*)ws;              ws += (size_t)3072 * 1024 * 2;
    u16* wo     = (u16*)ws;              ws += (size_t)1024 * 1024 * 2;  // contiguous after wqkv
    u16* qkvlin = (u16*)ws;              ws += (size_t)8192 * 3072 * 2;
    u16* vT     = (u16*)ws;              ws += (size_t)64 * 64 * 2048 * 2;

    prep_kernel<<<256, 256, 0, stream>>>(th, qb, vb, tab, qkvb);
    cvt_kernel<<<8192, 256, 0, stream>>>(x, xb, 2097152);
    cvt4_kernel<<<4096, 256, 0, stream>>>(qw, kw, vw, ow, wqkv);
    gemm_bt<1, 1><<<dim3(64, 24), 256, 0, stream>>>(xb, wqkv, qkvb, qkvlin, 8192, 3072, 1024, 1024);
    rope_vt_kernel<<<dim3(32, 64), 256, 0, stream>>>(qkvlin, tab, vT);
    attn_kernel<<<dim3(16, 64), 256, 0, stream>>>(qkvlin, vT);
    gemm_bt<0, 1><<<dim3(64, 8), 256, 0, stream>>>(qkvlin + 2048, wo, ob, d_out, 8192, 1024, 1024, 3072);
}

// Round 8
// 368.921 us; speedup vs baseline: 1.4532x; 1.2773x over previous
//
#include <hip/hip_runtime.h>
#include <math.h>

#define DEV __device__ __forceinline__

typedef unsigned int u32;
typedef unsigned short u16;
typedef __attribute__((ext_vector_type(4)))  float f32x4;
typedef __attribute__((ext_vector_type(16))) float f32x16;
typedef __attribute__((ext_vector_type(2)))  float f32x2;
typedef __attribute__((ext_vector_type(8)))  __bf16 bf16x8;
typedef __attribute__((ext_vector_type(4)))  u32 u32x4;

constexpr int B_ = 4, S_ = 2048, H_ = 16;
// D=1024, HD=64, HD2=32, rows = B*S = 8192, qkv width = 3072

DEV u16 f2bf(float f) {
    u32 u = __float_as_uint(f);
    return (u16)((u + 0x7fffu + ((u >> 16) & 1u)) >> 16);
}
DEV float bf2f(u16 x) { return __uint_as_float((u32)x << 16); }

DEV u32 cvtpk_bf16(float lo, float hi) {
    u32 r;
    asm("v_cvt_pk_bf16_f32 %0, %1, %2" : "=v"(r) : "v"(lo), "v"(hi));
    return r;
}

DEV void g2lds16(const void* g, void* l) {
    __builtin_amdgcn_global_load_lds(
        (__attribute__((address_space(1))) void*)(uintptr_t)g,
        (__attribute__((address_space(3))) void*)(u32)(uintptr_t)l,
        16, 0, 0);
}

// ---------------- prep: cos/sin table + fused qkv bias ----------------
__global__ void prep_kernel(const float* __restrict__ theta,
                            const float* __restrict__ qb,
                            const float* __restrict__ vb,
                            f32x2* __restrict__ tab,
                            float* __restrict__ qkvbias) {
    const int idx = blockIdx.x * 256 + threadIdx.x;   // 65536 threads = 2048*32
    if (idx < 3072)
        qkvbias[idx] = idx < 1024 ? qb[idx] : (idx < 2048 ? 0.0f : vb[idx - 2048]);
    const int s = idx >> 5, f = idx & 31;
    const double MEL = 2595.0 * log10(1.0 + 8000.0 / 700.0);
    float step = (float)MEL / 31.0f;
    float linf = (float)f * step;
    float y = linf / 2595.0f;
    double p = pow(10.0, (double)y);
    float pf = (float)p;
    float t1 = theta[0] / 220.0f * 700.0f;
    float freq = t1 * (pf - 1.0f) / 1000.0f;
    float ang = (float)s * freq;        // f32 product, like reference
    double da = (double)ang;
    f32x2 cs;
    cs.x = (float)cos(da);
    cs.y = (float)sin(da);
    tab[idx] = cs;
}

// ---------------- fp32 -> bf16 conversion (x) ----------------
__global__ void cvt_kernel(const float* __restrict__ src, u16* __restrict__ dst, int n4) {
    int i = blockIdx.x * 256 + threadIdx.x;
    if (i >= n4) return;
    float4 v = reinterpret_cast<const float4*>(src)[i];
    ushort4 o;
    o.x = f2bf(v.x); o.y = f2bf(v.y); o.z = f2bf(v.z); o.w = f2bf(v.w);
    reinterpret_cast<ushort4*>(dst)[i] = o;
}

// ---------------- fused weight conversion: qw|kw|vw|ow -> contiguous dst ----
__global__ void cvt4_kernel(const float* __restrict__ s0, const float* __restrict__ s1,
                            const float* __restrict__ s2, const float* __restrict__ s3,
                            u16* __restrict__ dst) {
    int i = blockIdx.x * 256 + threadIdx.x;          // 0 .. 1048575
    int seg = i >> 18;
    const float* src = seg == 0 ? s0 : seg == 1 ? s1 : seg == 2 ? s2 : s3;
    float4 v = reinterpret_cast<const float4*>(src)[i & 0x3FFFF];
    ushort4 o;
    o.x = f2bf(v.x); o.y = f2bf(v.y); o.z = f2bf(v.z); o.w = f2bf(v.w);
    reinterpret_cast<ushort4*>(dst)[i] = o;
}

// ---------------- GEMM  C[M,N] = A[M,K] * Bt[N,K]^T (+bias) ----------------
template <int OUT_BF16, int HAS_BIAS>
__global__ __launch_bounds__(256)
void gemm_bt(const u16* __restrict__ A, const u16* __restrict__ Bt,
             const float* __restrict__ bias, void* __restrict__ Cout,
             int M, int N, int K, int lda) {
    __shared__ u16 lA[128 * 64];
    __shared__ u16 lB[128 * 64];
    const int tid = threadIdx.x;
    const int lane = tid & 63, wave = tid >> 6;
    const int wr = wave >> 1, wc = wave & 1;
    const int m0 = blockIdx.x * 128, n0 = blockIdx.y * 128;
    const int fr = lane & 15, fk = (lane >> 4) * 8;
    const int stRow = tid >> 3;            // 0..31
    const int stCol = (tid & 7) * 8;       // 0..56

    f32x4 acc[4][4];
#pragma unroll
    for (int m = 0; m < 4; ++m)
#pragma unroll
        for (int n = 0; n < 4; ++n) acc[m][n] = (f32x4)0.0f;

    for (int k0 = 0; k0 < K; k0 += 64) {
#pragma unroll
        for (int i = 0; i < 4; ++i) {
            int row = i * 32 + stRow;
            int e = row * 64 + stCol;
            g2lds16(A + (size_t)(m0 + row) * lda + (k0 + stCol), &lA[e]);
            g2lds16(Bt + (size_t)(n0 + row) * K + (k0 + stCol), &lB[e]);
        }
        __syncthreads();
#pragma unroll
        for (int kk = 0; kk < 2; ++kk) {
            bf16x8 af[4], bg[4];
#pragma unroll
            for (int m = 0; m < 4; ++m)
                af[m] = *reinterpret_cast<const bf16x8*>(&lA[(wr * 64 + m * 16 + fr) * 64 + kk * 32 + fk]);
#pragma unroll
            for (int n = 0; n < 4; ++n)
                bg[n] = *reinterpret_cast<const bf16x8*>(&lB[(wc * 64 + n * 16 + fr) * 64 + kk * 32 + fk]);
#pragma unroll
            for (int m = 0; m < 4; ++m)
#pragma unroll
                for (int n = 0; n < 4; ++n)
                    acc[m][n] = __builtin_amdgcn_mfma_f32_16x16x32_bf16(af[m], bg[n], acc[m][n], 0, 0, 0);
        }
        __syncthreads();
    }
#pragma unroll
    for (int n = 0; n < 4; ++n) {
        int col = n0 + wc * 64 + n * 16 + fr;
        float bv = HAS_BIAS ? bias[col] : 0.0f;
#pragma unroll
        for (int m = 0; m < 4; ++m) {
            int r0 = m0 + wr * 64 + m * 16 + (lane >> 4) * 4;
#pragma unroll
            for (int j = 0; j < 4; ++j) {
                float v = acc[m][n][j] + bv;
                if (OUT_BF16)
                    ((u16*)Cout)[(size_t)(r0 + j) * N + col] = f2bf(v);
                else
                    ((float*)Cout)[(size_t)(r0 + j) * N + col] = v;
            }
        }
    }
}

// ---------------- rope (Q in-place, K packed) + V^T packed tiles ----------------
// kP[bh][t][slot]: slot = c*32+lr (c=16B chunk 0..7, lr=row 0..31),
//   content = roped K[t*32+lr][8c..8c+8)   (4KB per tile, staging-linear)
// vP[bh][t][slot]: slot = c*64+hd (c=s-chunk 0..3, hd=row 0..63),
//   content = V^T[hd][t*32+8c..+8)         (4KB per tile)
__global__ __launch_bounds__(256)
void rope_pack_kernel(u16* __restrict__ qkv, const f32x2* __restrict__ tab,
                      u16* __restrict__ kP, u16* __restrict__ vP) {
    __shared__ __align__(16) u16 lv[64][66];
    const int t = threadIdx.x;
    const int sblk = blockIdx.x;       // 0..31
    const int bh = blockIdx.y;         // 0..63
    const int b = bh >> 4, h = bh & 15;
    const int s0 = sblk * 64;
    const int t0 = sblk * 2;

    // ---- Q rope in-place ----
    const int f = t & 31, sl0 = t >> 5;
#pragma unroll
    for (int i = 0; i < 8; ++i) {
        int sl = i * 8 + sl0;
        int s = s0 + sl;
        f32x2 cs = tab[(s << 5) + f];
        size_t ro = (size_t)(b * S_ + s) * 3072 + h * 64 + 2 * f;
        u32* pq = (u32*)(qkv + ro);
        u32 vq = *pq;
        float a = bf2f((u16)(vq & 0xffff)), bb = bf2f((u16)(vq >> 16));
        *pq = (u32)f2bf(a * cs.x - bb * cs.y) | ((u32)f2bf(a * cs.y + bb * cs.x) << 16);
    }

    // ---- K rope + chunk-major pack ----
    {
        const int c = t & 7, sl = t >> 3;      // chunk, row-in-tile
#pragma unroll
        for (int i = 0; i < 2; ++i) {
            int s = s0 + 32 * i + sl;
            const u16* src = qkv + (size_t)(b * S_ + s) * 3072 + 1024 + h * 64 + c * 8;
            ushort4 w01 = *(const ushort4*)(src);
            ushort4 w23 = *(const ushort4*)(src + 4);
            u16 e[8] = {w01.x, w01.y, w01.z, w01.w, w23.x, w23.y, w23.z, w23.w};
            u32 ow[4];
#pragma unroll
            for (int j = 0; j < 4; ++j) {
                f32x2 cs = tab[(s << 5) + 4 * c + j];
                float a = bf2f(e[2 * j]), bb = bf2f(e[2 * j + 1]);
                ow[j] = (u32)f2bf(a * cs.x - bb * cs.y) | ((u32)f2bf(a * cs.y + bb * cs.x) << 16);
            }
            int tt = t0 + i;
            u32x4 ov = {ow[0], ow[1], ow[2], ow[3]};
            *(u32x4*)(kP + ((size_t)(bh * 64 + tt) * 2048 + (c * 32 + sl) * 8)) = ov;
        }
    }

    // ---- V transpose via LDS ----
#pragma unroll
    for (int i = 0; i < 4; ++i) {
        int u = i * 256 + t;
        int sl = u >> 4, hd = (u & 15) * 4;
        ushort4 vv = *(const ushort4*)(qkv + (size_t)(b * S_ + s0 + sl) * 3072 + 2048 + h * 64 + hd);
        lv[sl][hd] = vv.x; lv[sl][hd + 1] = vv.y; lv[sl][hd + 2] = vv.z; lv[sl][hd + 3] = vv.w;
    }
    __syncthreads();
    // ---- write V^T chunk-major tiles ----
    {
        const int c = t >> 6, hd = t & 63;
#pragma unroll
        for (int i = 0; i < 2; ++i) {
            int tt = t0 + i;
            int r0 = 32 * i + 8 * c;
            u16 e0 = lv[r0 + 0][hd], e1 = lv[r0 + 1][hd], e2 = lv[r0 + 2][hd], e3 = lv[r0 + 3][hd];
            u16 e4 = lv[r0 + 4][hd], e5 = lv[r0 + 5][hd], e6 = lv[r0 + 6][hd], e7 = lv[r0 + 7][hd];
            u32x4 ov = {(u32)e0 | ((u32)e1 << 16), (u32)e2 | ((u32)e3 << 16),
                        (u32)e4 | ((u32)e5 << 16), (u32)e6 | ((u32)e7 << 16)};
            *(u32x4*)(vP + ((size_t)(bh * 64 + tt) * 2048 + (c * 64 + hd) * 8)) = ov;
        }
    }
}

// ---------------- flash attention (block-cooperative LDS staging) ----------------
// 4 waves x 32 q-rows, KVBLK=32. K/V tiles shared via LDS double-buffer
// (global_load_lds from packed kP/vP, linear 16B/lane). One __syncthreads per
// tile: barrier drains last iter's stage; this iter's stage issued right after,
// hides under compute. Chunk-major LDS layout -> all ds_read_b128 conflict-free.
// Swapped QK^T (mfma(K,Q)), O^T = mfma(V^T,P^T), defer-max, cvt_pk+shfl P-pack.
__global__ __launch_bounds__(256)
void attn_kernel(u16* __restrict__ qkv, const u16* __restrict__ kP,
                 const u16* __restrict__ vP) {
    __shared__ __align__(16) u16 lk[2][2048];
    __shared__ __align__(16) u16 lvs[2][2048];
    const int tid = threadIdx.x;
    const int lane = tid & 63, wave = tid >> 6;
    const int qblk = blockIdx.x;       // 0..15
    const int bh = blockIdx.y;         // 0..63
    const int b = bh >> 4, h = bh & 15;
    const int q0 = qblk * 128 + wave * 32;
    const int lr = lane & 31;
    const int hi = lane >> 5;
    const int fo = hi * 8;

    bf16x8 qf[4];
    const u16* qrow = qkv + (size_t)(b * S_ + q0 + lr) * 3072 + h * 64 + fo;
#pragma unroll
    for (int ks = 0; ks < 4; ++ks)
        qf[ks] = *reinterpret_cast<const bf16x8*>(qrow + ks * 16);

    const u16* kT = kP + (size_t)bh * 64 * 2048;
    const u16* vT = vP + (size_t)bh * 64 * 2048;

    // wave w stages instrs {2w, 2w+1}: n<4 -> K slots n*64+lane, else V
#define STAGE(BUF, TT) do {                                                       \
        int n_ = wave * 2;                                                        \
        if (n_ < 4) {                                                             \
            g2lds16(kT + (size_t)(TT) * 2048 + (n_ * 64 + lane) * 8,              \
                    &lk[BUF][(n_ * 64 + lane) * 8]);                              \
            g2lds16(kT + (size_t)(TT) * 2048 + ((n_ + 1) * 64 + lane) * 8,        \
                    &lk[BUF][((n_ + 1) * 64 + lane) * 8]);                        \
        } else {                                                                  \
            int m_ = n_ - 4;                                                      \
            g2lds16(vT + (size_t)(TT) * 2048 + (m_ * 64 + lane) * 8,              \
                    &lvs[BUF][(m_ * 64 + lane) * 8]);                             \
            g2lds16(vT + (size_t)(TT) * 2048 + ((m_ + 1) * 64 + lane) * 8,        \
                    &lvs[BUF][((m_ + 1) * 64 + lane) * 8]);                       \
        }                                                                         \
    } while (0)

    f32x16 o0 = (f32x16)0.0f, o1 = (f32x16)0.0f;
    float ms = -3.0e38f, l = 0.0f;
    const float c1 = 0.125f * 1.44269504088896340736f;  // scale * log2(e)

    STAGE(0, 0);
    int buf = 0;
    for (int t = 0; t < 64; ++t) {
        __syncthreads();               // drains prior stage; read-safety for buf^1
        if (t < 63) STAGE(buf ^ 1, t + 1);

        // K frags: slot = c*32+lr, c = 2k+hi
        bf16x8 kf0 = *reinterpret_cast<const bf16x8*>(&lk[buf][((0 + hi) * 32 + lr) * 8]);
        bf16x8 kf1 = *reinterpret_cast<const bf16x8*>(&lk[buf][((2 + hi) * 32 + lr) * 8]);
        bf16x8 kf2 = *reinterpret_cast<const bf16x8*>(&lk[buf][((4 + hi) * 32 + lr) * 8]);
        bf16x8 kf3 = *reinterpret_cast<const bf16x8*>(&lk[buf][((6 + hi) * 32 + lr) * 8]);
        f32x16 s = (f32x16)0.0f;
        s = __builtin_amdgcn_mfma_f32_32x32x16_bf16(kf0, qf[0], s, 0, 0, 0);
        s = __builtin_amdgcn_mfma_f32_32x32x16_bf16(kf1, qf[1], s, 0, 0, 0);
        s = __builtin_amdgcn_mfma_f32_32x32x16_bf16(kf2, qf[2], s, 0, 0, 0);
        s = __builtin_amdgcn_mfma_f32_32x32x16_bf16(kf3, qf[3], s, 0, 0, 0);

        // V frags: slot = c*64+row
        bf16x8 vf00 = *reinterpret_cast<const bf16x8*>(&lvs[buf][((0 + hi) * 64 + lr) * 8]);
        bf16x8 vf01 = *reinterpret_cast<const bf16x8*>(&lvs[buf][((2 + hi) * 64 + lr) * 8]);
        bf16x8 vf10 = *reinterpret_cast<const bf16x8*>(&lvs[buf][((0 + hi) * 64 + lr + 32) * 8]);
        bf16x8 vf11 = *reinterpret_cast<const bf16x8*>(&lvs[buf][((2 + hi) * 64 + lr + 32) * 8]);

        // tree max over 16 raw scores
        float t0_ = fmaxf(fmaxf(s[0], s[1]), fmaxf(s[2], s[3]));
        float t1_ = fmaxf(fmaxf(s[4], s[5]), fmaxf(s[6], s[7]));
        float t2_ = fmaxf(fmaxf(s[8], s[9]), fmaxf(s[10], s[11]));
        float t3_ = fmaxf(fmaxf(s[12], s[13]), fmaxf(s[14], s[15]));
        float mt = fmaxf(fmaxf(t0_, t1_), fmaxf(t2_, t3_));
        mt = fmaxf(mt, __shfl_xor(mt, 32));
        float mts = mt * c1;
        if (!__all(mts - ms <= 6.0f)) {
            float msn = fmaxf(ms, mts);
            float alpha = exp2f(ms - msn);
            ms = msn;
            l *= alpha;
            o0 = o0 * alpha;
            o1 = o1 * alpha;
        }
        float pv[16];
        float ps = 0.0f;
#pragma unroll
        for (int r = 0; r < 16; ++r) {
            pv[r] = exp2f(fmaf(s[r], c1, -ms));
            ps += pv[r];
        }
        l += ps;
        u32 d00, d01, d02, d03, d10, d11, d12, d13;
        {
            u32 a0 = cvtpk_bf16(pv[0], pv[1]);
            u32 a1 = cvtpk_bf16(pv[2], pv[3]);
            u32 b0 = cvtpk_bf16(pv[4], pv[5]);
            u32 b1 = cvtpk_bf16(pv[6], pv[7]);
            u32 xa0 = (u32)__shfl_xor((int)a0, 32), xa1 = (u32)__shfl_xor((int)a1, 32);
            u32 xb0 = (u32)__shfl_xor((int)b0, 32), xb1 = (u32)__shfl_xor((int)b1, 32);
            d00 = hi ? xb0 : a0;  d01 = hi ? xb1 : a1;
            d02 = hi ? b0 : xa0;  d03 = hi ? b1 : xa1;
        }
        {
            u32 a0 = cvtpk_bf16(pv[8], pv[9]);
            u32 a1 = cvtpk_bf16(pv[10], pv[11]);
            u32 b0 = cvtpk_bf16(pv[12], pv[13]);
            u32 b1 = cvtpk_bf16(pv[14], pv[15]);
            u32 xa0 = (u32)__shfl_xor((int)a0, 32), xa1 = (u32)__shfl_xor((int)a1, 32);
            u32 xb0 = (u32)__shfl_xor((int)b0, 32), xb1 = (u32)__shfl_xor((int)b1, 32);
            d10 = hi ? xb0 : a0;  d11 = hi ? xb1 : a1;
            d12 = hi ? b0 : xa0;  d13 = hi ? b1 : xa1;
        }
        u32x4 tt0 = {d00, d01, d02, d03};
        u32x4 tt1 = {d10, d11, d12, d13};
        bf16x8 p0 = __builtin_bit_cast(bf16x8, tt0);
        bf16x8 p1 = __builtin_bit_cast(bf16x8, tt1);

        o0 = __builtin_amdgcn_mfma_f32_32x32x16_bf16(vf00, p0, o0, 0, 0, 0);
        o0 = __builtin_amdgcn_mfma_f32_32x32x16_bf16(vf01, p1, o0, 0, 0, 0);
        o1 = __builtin_amdgcn_mfma_f32_32x32x16_bf16(vf10, p0, o1, 0, 0, 0);
        o1 = __builtin_amdgcn_mfma_f32_32x32x16_bf16(vf11, p1, o1, 0, 0, 0);
        buf ^= 1;
    }
#undef STAGE

    l += __shfl_xor(l, 32);
    float inv = 1.0f / l;
    u16* orow = qkv + (size_t)(b * S_ + q0 + lr) * 3072 + 2048 + h * 64;
#pragma unroll
    for (int g = 0; g < 4; ++g) {
        ushort4 w0, w1;
        w0.x = f2bf(o0[4 * g + 0] * inv); w0.y = f2bf(o0[4 * g + 1] * inv);
        w0.z = f2bf(o0[4 * g + 2] * inv); w0.w = f2bf(o0[4 * g + 3] * inv);
        *(ushort4*)(orow + 8 * g + 4 * hi) = w0;
        w1.x = f2bf(o1[4 * g + 0] * inv); w1.y = f2bf(o1[4 * g + 1] * inv);
        w1.z = f2bf(o1[4 * g + 2] * inv); w1.w = f2bf(o1[4 * g + 3] * inv);
        *(ushort4*)(orow + 32 + 8 * g + 4 * hi) = w1;
    }
}

// ---------------- launch ----------------
extern "C" void kernel_launch(void* const* d_in, const int* in_sizes, int n_in,
                              void* d_out, int out_size, void* d_ws, size_t ws_size,
                              hipStream_t stream) {
    const float* x  = (const float*)d_in[0];
    const float* qw = (const float*)d_in[1];
    const float* qb = (const float*)d_in[2];
    const float* kw = (const float*)d_in[3];
    const float* vw = (const float*)d_in[4];
    const float* vb = (const float*)d_in[5];
    const float* ow = (const float*)d_in[6];
    const float* ob = (const float*)d_in[7];
    const float* th = (const float*)d_in[8];

    char* ws = (char*)d_ws;
    f32x2* tab  = (f32x2*)ws;            ws += (size_t)2048 * 32 * 8;
    float* qkvb = (float*)ws;            ws += 3072 * 4;
    u16* xb     = (u16*)ws;              ws += (size_t)8192 * 1024 * 2;   // reused as kP after gemm1
    u16* wqkv   = (u16*)ws;              ws += (size_t)3072 * 1024 * 2;
    u16* wo     = (u16*)ws;              ws += (size_t)1024 * 1024 * 2;
    u16* qkvlin = (u16*)ws;              ws += (size_t)8192 * 3072 * 2;
    u16* vP     = (u16*)ws;              ws += (size_t)64 * 64 * 2048 * 2;
    u16* kP     = xb;  // overlay: xb dead after gemm1

    prep_kernel<<<256, 256, 0, stream>>>(th, qb, vb, tab, qkvb);
    cvt_kernel<<<8192, 256, 0, stream>>>(x, xb, 2097152);
    cvt4_kernel<<<4096, 256, 0, stream>>>(qw, kw, vw, ow, wqkv);
    gemm_bt<1, 1><<<dim3(64, 24), 256, 0, stream>>>(xb, wqkv, qkvb, qkvlin, 8192, 3072, 1024, 1024);
    rope_pack_kernel<<<dim3(32, 64), 256, 0, stream>>>(qkvlin, tab, kP, vP);
    attn_kernel<<<dim3(16, 64), 256, 0, stream>>>(qkvlin, kP, vP);
    gemm_bt<0, 1><<<dim3(64, 8), 256, 0, stream>>>(qkvlin + 2048, wo, ob, d_out, 8192, 1024, 1024, 3072);
}